// Round 4
// baseline (594.063 us; speedup 1.0000x reference)
//
#include <hip/hip_runtime.h>

// ---------------- constants ----------------
#define T_TOK 4096      // B*S
#define DIM   1024
#define KS    1024      // STATE
#define HSEL  128
#define NE    4
#define DFF   4096
#define NCAT  1152      // KS + HSEL fused N
#define CHK   32        // scan chunk length

typedef unsigned short u16;
typedef __attribute__((ext_vector_type(8))) __bf16 bf16x8;
typedef __attribute__((ext_vector_type(4))) float  f32x4;

__device__ __forceinline__ u16 f2bf(float f) {
  union { float f; unsigned int u; } v; v.f = f;
  unsigned int u = v.u;
  return (u16)((u + 0x7fffu + ((u >> 16) & 1u)) >> 16);
}
__device__ __forceinline__ float bf2f(u16 h) {
  union { unsigned int u; float f; } v; v.u = ((unsigned int)h) << 16;
  return v.f;
}
__device__ __forceinline__ float sigm(float x)  { return 1.0f / (1.0f + __expf(-x)); }
__device__ __forceinline__ float tanhf2(float x){ return 1.0f - 2.0f / (1.0f + __expf(2.0f * x)); }

__device__ __forceinline__ void async_ld16(const void* g, void* l) {
  __builtin_amdgcn_global_load_lds(
      (const __attribute__((address_space(1))) unsigned int*)g,
      (__attribute__((address_space(3))) unsigned int*)l, 16, 0, 0);
}

__device__ __forceinline__ f32x4 mfma16(bf16x8 a, bf16x8 b, f32x4 c) {
  return __builtin_amdgcn_mfma_f32_16x16x32_bf16(a, b, c, 0, 0, 0);
}

// ---------------- transpose + fp32->bf16 convert ----------------
__global__ void transpose_bf16(const float* __restrict__ in, u16* __restrict__ out,
                               int R, int C, int orow0, int obrows) {
  const float* inb = in + (size_t)blockIdx.z * R * C;
  u16* outb = out + (size_t)blockIdx.z * obrows * R;
  __shared__ u16 tile[32][33];
  int c0 = blockIdx.x * 32, r0 = blockIdx.y * 32;
  int tx = threadIdx.x, ty = threadIdx.y;   // block (32,8)
#pragma unroll
  for (int i = 0; i < 4; i++) {
    int r = r0 + ty + i * 8;
    tile[ty + i * 8][tx] = f2bf(inb[(size_t)r * C + c0 + tx]);
  }
  __syncthreads();
#pragma unroll
  for (int i = 0; i < 4; i++) {
    int c = c0 + ty + i * 8;
    outb[(size_t)(orow0 + c) * R + r0 + tx] = tile[tx][ty + i * 8];
  }
}

// ---------------- routing ----------------
__global__ void routing_kernel(const int* __restrict__ token_ids,
                               int* __restrict__ perm, int* __restrict__ tpos,
                               int* __restrict__ goff) {
  __shared__ int cnt[256 * 8];
  __shared__ int btot[8];
  __shared__ int bbase[8];
  int t = threadIdx.x;
  int lc[8]; int myg[16];
#pragma unroll
  for (int j = 0; j < 8; j++) lc[j] = 0;
#pragma unroll
  for (int i = 0; i < 16; i++) {
    int tok = t * 16 + i;
    unsigned int h = (unsigned int)token_ids[tok];
    h ^= h >> 16; h *= 2246822507u; h ^= h >> 13; h *= 3266489909u; h ^= h >> 16;
    int route = (int)(h & 3u);
    int g = route * 2 + (tok >> 11);   // (expert, batch)
    myg[i] = g; lc[g]++;
  }
#pragma unroll
  for (int j = 0; j < 8; j++) cnt[t * 8 + j] = lc[j];
  __syncthreads();
  int wave = t >> 6, lane = t & 63;
  for (int j = wave * 2; j < wave * 2 + 2; j++) {
    int v0 = cnt[(4 * lane + 0) * 8 + j];
    int v1 = cnt[(4 * lane + 1) * 8 + j];
    int v2 = cnt[(4 * lane + 2) * 8 + j];
    int v3 = cnt[(4 * lane + 3) * 8 + j];
    int s = v0 + v1 + v2 + v3;
    int inc = s;
    for (int d = 1; d < 64; d <<= 1) {
      int o = __shfl_up(inc, d);
      if (lane >= d) inc += o;
    }
    int excl = inc - s;
    cnt[(4 * lane + 0) * 8 + j] = excl;
    cnt[(4 * lane + 1) * 8 + j] = excl + v0;
    cnt[(4 * lane + 2) * 8 + j] = excl + v0 + v1;
    cnt[(4 * lane + 3) * 8 + j] = excl + v0 + v1 + v2;
    if (lane == 63) btot[j] = inc;
  }
  __syncthreads();
  if (t == 0) {
    int run = 0;
    for (int j = 0; j < 8; j++) { bbase[j] = run; goff[j] = run; run += btot[j]; }
    goff[8] = run;
  }
  __syncthreads();
  int pos[8];
#pragma unroll
  for (int j = 0; j < 8; j++) pos[j] = bbase[j] + cnt[t * 8 + j];
#pragma unroll
  for (int i = 0; i < 16; i++) {
    int g = myg[i];
    int tok = t * 16 + i;
    perm[pos[g]] = tok;
    tpos[tok] = pos[g];
    pos[g]++;
  }
}

// ---------------- elementwise: (optional residual mix) + rmsnorm -> bf16 ----------------
// MIX variant scatter-writes the normalized row to xs[tpos[row]] (expert-sorted order).
template <bool MIX>
__global__ void ew_rms(const float* __restrict__ in, const float* __restrict__ in2,
                       const float* __restrict__ mix, float* __restrict__ mix_out,
                       const int* __restrict__ tpos, u16* __restrict__ nrm_out) {
  int row = blockIdx.x;
  int t = threadIdx.x;
  size_t base = (size_t)row * DIM + t * 4;
  float4 v;
  if (MIX) {
    float4 a = *(const float4*)(in + base);
    float4 b = *(const float4*)(in2 + base);
    float4 m0 = *(const float4*)(mix + t * 4);
    float4 m1 = *(const float4*)(mix + DIM + t * 4);
    v.x = m0.x * a.x + m1.x * b.x;
    v.y = m0.y * a.y + m1.y * b.y;
    v.z = m0.z * a.z + m1.z * b.z;
    v.w = m0.w * a.w + m1.w * b.w;
    *(float4*)(mix_out + base) = v;
  } else {
    v = *(const float4*)(in + base);
  }
  float ss = v.x * v.x + v.y * v.y + v.z * v.z + v.w * v.w;
#pragma unroll
  for (int d = 32; d >= 1; d >>= 1) ss += __shfl_xor(ss, d);
  __shared__ float red[4];
  int wave = t >> 6, lane = t & 63;
  if (lane == 0) red[wave] = ss;
  __syncthreads();
  float tot = red[0] + red[1] + red[2] + red[3];
  float sc = rsqrtf(tot * (1.0f / (float)DIM) + 1e-6f);
  ushort4 o;
  o.x = f2bf(v.x * sc); o.y = f2bf(v.y * sc); o.z = f2bf(v.z * sc); o.w = f2bf(v.w * sc);
  size_t obase = MIX ? ((size_t)tpos[row] * DIM + t * 4) : base;
  *(ushort4*)(nrm_out + obase) = o;
}

// ---------------- GEMM: TM x TN tile, BK=32, 3-buffer distance-2 async pipeline ----------------
// Raw s_waitcnt vmcnt(ITERS)+s_barrier keeps next slab's global_load_lds in flight
// across the barrier (AITER pattern). LDS phys chunk p of row r holds logical p^((r>>1)&3).
// AMODE: 1 = A rows compact (grouped via goff), 2 = dense M
// EPI: 0 f32 | 2 bf16 | 3 ssm residual scatter via perm | 4 relu^2 bf16 | 5 mlp residual
//      | 6 fused: col<KS -> f32 u, col>=KS -> silu bf16 sh
template <int TM, int TN, int AMODE, int EPI>
__global__ __launch_bounds__(256, 2)
void gemm_t(const u16* __restrict__ A, const u16* __restrict__ Bt,
            int K, int Ntot, int Mfixed,
            const int* __restrict__ perm, const int* __restrict__ goff,
            float* __restrict__ outf, u16* __restrict__ outb,
            const float* __restrict__ xres, const float* __restrict__ svec) {
  constexpr int BK = 32;
  constexpr int CH_A = TM * 4;            // 16B chunks per BK-slab of A
  constexpr int CH_B = TN * 4;
  constexpr int ITERS = (CH_A + CH_B) / 256;
  constexpr int ATM = 4;                  // wave m-extent 64
  constexpr int ATN = TN / 32;
  static_assert(CH_A % 256 == 0, "A/B staging boundary must align to wave iters");

  int e = blockIdx.z;
  int row_start, row_end;
  if (AMODE == 2) { row_start = 0; row_end = Mfixed; }
  else { row_start = goff[2 * e]; row_end = goff[2 * e + 2]; }
  int m0 = row_start + blockIdx.x * TM;
  if (m0 >= row_end) return;
  int n0 = blockIdx.y * TN;
  const u16* Bte = Bt + (size_t)e * Ntot * K;

  __shared__ __align__(16) u16 As[3][TM * BK];
  __shared__ __align__(16) u16 Bs[3][TN * BK];

  int tid = threadIdx.x;
  int wave = tid >> 6, lane = tid & 63;
  int wm = wave & 1, wn = wave >> 1;
  int lrow = lane & 15, lq = lane >> 4;

  const u16* gptr[ITERS];
#pragma unroll
  for (int i = 0; i < ITERS; i++) {
    int s = tid + i * 256;
    if (i * 256 < CH_A) {              // stages A
      int r = s >> 2;
      int c = (s & 3) ^ ((r >> 1) & 3);
      int gr = m0 + r;
      int cl = (AMODE == 2) ? gr : (gr < row_end ? gr : row_end - 1);
      gptr[i] = A + (size_t)cl * K + c * 8;
    } else {                           // stages B
      int s2 = s - CH_A;
      int r = s2 >> 2;
      int c = (s2 & 3) ^ ((r >> 1) & 3);
      gptr[i] = Bte + (size_t)(n0 + r) * K + c * 8;
    }
  }

  auto stage = [&](int buf, int k0) {
#pragma unroll
    for (int i = 0; i < ITERS; i++) {
      if (i * 256 < CH_A)
        async_ld16(gptr[i] + k0, &As[buf][(size_t)(i * 256 + wave * 64) * 8]);
      else
        async_ld16(gptr[i] + k0, &Bs[buf][(size_t)(i * 256 - CH_A + wave * 64) * 8]);
    }
  };

  f32x4 acc[ATM][ATN];
#pragma unroll
  for (int i = 0; i < ATM; i++)
#pragma unroll
    for (int j = 0; j < ATN; j++) acc[i][j] = (f32x4){0.f, 0.f, 0.f, 0.f};

  // fragment offsets within a buffer: row r at r*BK; phys chunk lq^((r>>1)&3)
  int aoff[ATM], boff[ATN];
#pragma unroll
  for (int tm = 0; tm < ATM; tm++) {
    int r = wm * 64 + tm * 16 + lrow;
    aoff[tm] = r * BK + (lq ^ ((r >> 1) & 3)) * 8;
  }
#pragma unroll
  for (int tn = 0; tn < ATN; tn++) {
    int r = wn * (ATN * 16) + tn * 16 + lrow;
    boff[tn] = r * BK + (lq ^ ((r >> 1) & 3)) * 8;
  }

  int nk = K / BK;
  stage(0, 0);
  stage(1, BK);
  int cur = 0;
  for (int k = 0; k < nk; ++k) {
    // Drain slab k (keep slab k+1's ITERS loads in flight across the barrier).
    if (k + 1 < nk) {
      asm volatile("s_waitcnt vmcnt(%0) lgkmcnt(0)\n\ts_barrier" :: "n"(ITERS) : "memory");
    } else {
      asm volatile("s_waitcnt vmcnt(0) lgkmcnt(0)\n\ts_barrier" ::: "memory");
    }
    if (k + 2 < nk) {
      int nb = cur + 2; if (nb >= 3) nb -= 3;
      stage(nb, (k + 2) * BK);
    }
    bf16x8 af[ATM], bb[ATN];
#pragma unroll
    for (int tm = 0; tm < ATM; tm++) af[tm] = *(const bf16x8*)&As[cur][aoff[tm]];
#pragma unroll
    for (int tn = 0; tn < ATN; tn++) bb[tn] = *(const bf16x8*)&Bs[cur][boff[tn]];
#pragma unroll
    for (int tm = 0; tm < ATM; tm++)
#pragma unroll
      for (int tn = 0; tn < ATN; tn++)
        acc[tm][tn] = mfma16(af[tm], bb[tn], acc[tm][tn]);
    cur += 1; if (cur >= 3) cur = 0;
  }

  // epilogue: C/D layout col = lane&15, row = (lane>>4)*4 + reg
#pragma unroll
  for (int tm = 0; tm < ATM; tm++) {
    int rowb = m0 + wm * 64 + tm * 16 + lq * 4;
#pragma unroll
    for (int tn = 0; tn < ATN; tn++) {
      int col = n0 + wn * (ATN * 16) + tn * 16 + lrow;
#pragma unroll
      for (int r = 0; r < 4; r++) {
        int row = rowb + r;
        if (AMODE != 2 && row >= row_end) continue;
        float v = acc[tm][tn][r];
        if (EPI == 0) {
          outf[(size_t)row * Ntot + col] = v;
        } else if (EPI == 2) {
          outb[(size_t)row * Ntot + col] = f2bf(v);
        } else if (EPI == 3) {
          int tok = perm[row];
          size_t o = (size_t)tok * DIM + col;
          outf[o] = xres[o] + svec[col] * v;
        } else if (EPI == 4) {
          float t2 = fmaxf(v, 0.f);
          outb[(size_t)row * Ntot + col] = f2bf(t2 * t2);
        } else if (EPI == 5) {
          size_t o = (size_t)row * DIM + col;
          outf[o] = xres[o] + svec[col] * v;
        } else {  // EPI 6: fused u | silu(sel_in)
          if (col < KS) outf[(size_t)row * KS + col] = v;
          else outb[(size_t)row * HSEL + (col - KS)] = f2bf(v * sigm(v));
        }
      }
    }
  }
}

// ---------------- chunked linear scan: h = a*h + b*u ----------------
__global__ void scan_p1(const float* __restrict__ u, const u16* __restrict__ sel,
                        const int* __restrict__ goff,
                        float* __restrict__ P, float* __restrict__ S) {
  int g = blockIdx.y;
  int beg = goff[g], end = goff[g + 1];
  int i0 = beg + blockIdx.x * CHK;
  if (i0 >= end) return;
  int ie = i0 + CHK < end ? i0 + CHK : end;
  int k0 = threadIdx.x * 4;
  float h0 = 0, h1 = 0, h2 = 0, h3 = 0;
  float p0 = 1, p1 = 1, p2 = 1, p3 = 1;
  for (int i = i0; i < ie; ++i) {
    size_t sb = (size_t)i * 4096 + k0;
    float4 uv = *(const float4*)(u + (size_t)i * KS + k0);
    ushort4 av = *(const ushort4*)(sel + sb);
    ushort4 bv = *(const ushort4*)(sel + sb + 1024);
    float a0 = sigm(bf2f(av.x)), a1 = sigm(bf2f(av.y));
    float a2 = sigm(bf2f(av.z)), a3 = sigm(bf2f(av.w));
    float b0 = tanhf2(bf2f(bv.x)), b1 = tanhf2(bf2f(bv.y));
    float b2 = tanhf2(bf2f(bv.z)), b3 = tanhf2(bf2f(bv.w));
    h0 = a0 * h0 + b0 * uv.x; p0 *= a0;
    h1 = a1 * h1 + b1 * uv.y; p1 *= a1;
    h2 = a2 * h2 + b2 * uv.z; p2 *= a2;
    h3 = a3 * h3 + b3 * uv.w; p3 *= a3;
  }
  size_t ob = ((size_t)g * 128 + blockIdx.x) * KS + k0;
  *(float4*)(P + ob) = make_float4(p0, p1, p2, p3);
  *(float4*)(S + ob) = make_float4(h0, h1, h2, h3);
}

__global__ void scan_p2(const float* __restrict__ P, const float* __restrict__ S,
                        const int* __restrict__ goff, float* __restrict__ C) {
  int g = blockIdx.x;
  int k0 = blockIdx.y * 256 + threadIdx.x * 4;
  int beg = goff[g], end = goff[g + 1];
  int nch = (end - beg + CHK - 1) / CHK;
  float c0 = 0, c1 = 0, c2 = 0, c3 = 0;
#pragma unroll 4
  for (int ch = 0; ch < nch; ++ch) {
    size_t ob = ((size_t)g * 128 + ch) * KS + k0;
    float4 pv = *(const float4*)(P + ob);
    float4 sv = *(const float4*)(S + ob);
    *(float4*)(C + ob) = make_float4(c0, c1, c2, c3);
    c0 = pv.x * c0 + sv.x;
    c1 = pv.y * c1 + sv.y;
    c2 = pv.z * c2 + sv.z;
    c3 = pv.w * c3 + sv.w;
  }
}

__global__ void scan_p3(const float* __restrict__ u, const u16* __restrict__ sel,
                        const int* __restrict__ goff, const float* __restrict__ C,
                        const float* __restrict__ dpar, u16* __restrict__ yst) {
  int g = blockIdx.y;
  int e = g >> 1;
  int beg = goff[g], end = goff[g + 1];
  int i0 = beg + blockIdx.x * CHK;
  if (i0 >= end) return;
  int ie = i0 + CHK < end ? i0 + CHK : end;
  int k0 = threadIdx.x * 4;
  size_t ob = ((size_t)g * 128 + blockIdx.x) * KS + k0;
  float4 hv = *(const float4*)(C + ob);
  float4 dv = *(const float4*)(dpar + (size_t)e * KS + k0);
  float h0 = hv.x, h1 = hv.y, h2 = hv.z, h3 = hv.w;
  for (int i = i0; i < ie; ++i) {
    size_t sb = (size_t)i * 4096 + k0;
    float4 uv = *(const float4*)(u + (size_t)i * KS + k0);
    ushort4 av = *(const ushort4*)(sel + sb);
    ushort4 bv = *(const ushort4*)(sel + sb + 1024);
    ushort4 cv = *(const ushort4*)(sel + sb + 2048);
    ushort4 gv = *(const ushort4*)(sel + sb + 3072);
    float a0 = sigm(bf2f(av.x)), a1 = sigm(bf2f(av.y));
    float a2 = sigm(bf2f(av.z)), a3 = sigm(bf2f(av.w));
    float b0 = tanhf2(bf2f(bv.x)), b1 = tanhf2(bf2f(bv.y));
    float b2 = tanhf2(bf2f(bv.z)), b3 = tanhf2(bf2f(bv.w));
    float q0 = tanhf2(bf2f(cv.x)), q1 = tanhf2(bf2f(cv.y));
    float q2 = tanhf2(bf2f(cv.z)), q3 = tanhf2(bf2f(cv.w));
    float g0 = sigm(bf2f(gv.x)), g1 = sigm(bf2f(gv.y));
    float g2 = sigm(bf2f(gv.z)), g3 = sigm(bf2f(gv.w));
    h0 = a0 * h0 + b0 * uv.x;
    h1 = a1 * h1 + b1 * uv.y;
    h2 = a2 * h2 + b2 * uv.z;
    h3 = a3 * h3 + b3 * uv.w;
    ushort4 o;
    o.x = f2bf(q0 * h0 + dv.x * g0 * uv.x);
    o.y = f2bf(q1 * h1 + dv.y * g1 * uv.y);
    o.z = f2bf(q2 * h2 + dv.z * g2 * uv.z);
    o.w = f2bf(q3 * h3 + dv.w * g3 * uv.w);
    *(ushort4*)(yst + (size_t)i * KS + k0) = o;
  }
}

// ---------------- host launch ----------------
extern "C" void kernel_launch(void* const* d_in, const int* in_sizes, int n_in,
                              void* d_out, int out_size, void* d_ws, size_t ws_size,
                              hipStream_t stream) {
  const float* x      = (const float*)d_in[0];
  const float* x0     = (const float*)d_in[1];
  const float* W_in   = (const float*)d_in[2];
  const float* W_seli = (const float*)d_in[3];
  const float* W_selo = (const float*)d_in[4];
  const float* W_out  = (const float*)d_in[5];
  const float* d_par  = (const float*)d_in[6];
  const float* ssm_s  = (const float*)d_in[7];
  const float* mlp_s  = (const float*)d_in[8];
  const float* rmix   = (const float*)d_in[9];
  const float* W_fc   = (const float*)d_in[10];
  const float* W_proj = (const float*)d_in[11];
  const int*   tok    = (const int*)d_in[12];
  float* out = (float*)d_out;

  char* p = (char*)d_ws;
  u16* wt_cat  = (u16*)p; p += (size_t)NE * NCAT * DIM * 2;    // [e][1152][1024]
  u16* wt_selo = (u16*)p; p += (size_t)NE * 4 * KS * HSEL * 2; // [e][4KS][HSEL]
  u16* wt_out  = (u16*)p; p += (size_t)NE * DIM * KS * 2;      // [e][DIM][KS]
  u16* wt_fc   = (u16*)p; p += (size_t)DFF * DIM * 2;          // [DFF][DIM]
  u16* wt_pr   = (u16*)p; p += (size_t)DIM * DFF * 2;          // [DIM][DFF]
  u16* xs      = (u16*)p; p += (size_t)T_TOK * DIM * 2;        // permuted order
  u16* sh      = (u16*)p; p += (size_t)T_TOK * HSEL * 2;
  u16* sel     = (u16*)p; p += (size_t)T_TOK * 4 * KS * 2;
  u16* yst     = (u16*)p; p += (size_t)T_TOK * KS * 2;
  u16* xn2     = (u16*)p; p += (size_t)T_TOK * DIM * 2;
  u16* hmid    = (u16*)p; p += (size_t)T_TOK * DFF * 2;
  float* xmix = (float*)p; p += (size_t)T_TOK * DIM * 4;
  float* ubuf = (float*)p; p += (size_t)T_TOK * KS * 4;
  float* x2   = (float*)p; p += (size_t)T_TOK * DIM * 4;
  float* Pbuf = (float*)p; p += (size_t)8 * 128 * KS * 4;
  float* Sbuf = (float*)p; p += (size_t)8 * 128 * KS * 4;
  float* Cbuf = (float*)p; p += (size_t)8 * 128 * KS * 4;
  int* perm = (int*)p; p += (size_t)T_TOK * 4;
  int* tpos = (int*)p; p += (size_t)T_TOK * 4;
  int* goff = (int*)p; p += 16 * 4;

  dim3 tb(32, 8, 1);
  transpose_bf16<<<dim3(32, 32, NE), tb, 0, stream>>>(W_in, wt_cat, DIM, KS, 0, NCAT);
  transpose_bf16<<<dim3(4, 32, NE), tb, 0, stream>>>(W_seli, wt_cat, DIM, HSEL, KS, NCAT);
  transpose_bf16<<<dim3(128, 4, NE), tb, 0, stream>>>(W_selo, wt_selo, HSEL, 4 * KS, 0, 4 * KS);
  transpose_bf16<<<dim3(32, 32, NE), tb, 0, stream>>>(W_out, wt_out, KS, DIM, 0, DIM);
  transpose_bf16<<<dim3(128, 32, 1), tb, 0, stream>>>(W_fc, wt_fc, DIM, DFF, 0, DFF);
  transpose_bf16<<<dim3(32, 128, 1), tb, 0, stream>>>(W_proj, wt_pr, DFF, DIM, 0, DIM);

  routing_kernel<<<1, 256, 0, stream>>>(tok, perm, tpos, goff);
  // rmsnorm + scatter into expert-sorted xs (contiguous A for the grouped GEMMs)
  ew_rms<true><<<T_TOK, 256, 0, stream>>>(x, x0, rmix, xmix, tpos, xs);

  // fused u + silu(sel_in): grouped, N=1152, contiguous A
  gemm_t<128, 128, 1, 6><<<dim3(32, NCAT / 128, NE), 256, 0, stream>>>(
      xs, wt_cat, DIM, NCAT, 0, perm, goff, ubuf, sh, nullptr, nullptr);
  // sel_out: grouped, N=4096, K=128
  gemm_t<128, 128, 1, 2><<<dim3(32, 32, NE), 256, 0, stream>>>(
      sh, wt_selo, HSEL, 4 * KS, 0, perm, goff, nullptr, sel, nullptr, nullptr);
  // recurrence
  scan_p1<<<dim3(128, 8), 256, 0, stream>>>(ubuf, sel, goff, Pbuf, Sbuf);
  scan_p2<<<dim3(8, 4), 64, 0, stream>>>(Pbuf, Sbuf, goff, Cbuf);
  scan_p3<<<dim3(128, 8), 256, 0, stream>>>(ubuf, sel, goff, Cbuf, d_par, yst);
  // routed out-proj + residual scatter
  gemm_t<128, 64, 1, 3><<<dim3(32, 16, NE), 256, 0, stream>>>(
      yst, wt_out, KS, DIM, 0, perm, goff, x2, nullptr, xmix, ssm_s);
  // MLP
  ew_rms<false><<<T_TOK, 256, 0, stream>>>(x2, nullptr, nullptr, nullptr, nullptr, xn2);
  gemm_t<128, 128, 2, 4><<<dim3(32, 32, 1), 256, 0, stream>>>(
      xn2, wt_fc, DIM, DFF, T_TOK, nullptr, nullptr, nullptr, hmid, nullptr, nullptr);
  gemm_t<128, 64, 2, 5><<<dim3(32, 16, 1), 256, 0, stream>>>(
      hmid, wt_pr, DFF, DIM, T_TOK, nullptr, nullptr, out, nullptr, x2, mlp_s);
}

// Round 5
// 520.405 us; speedup vs baseline: 1.1415x; 1.1415x over previous
//
#include <hip/hip_runtime.h>

// ---------------- constants ----------------
#define T_TOK 4096      // B*S
#define DIM   1024
#define KS    1024      // STATE
#define HSEL  128
#define NE    4
#define DFF   4096
#define NCAT  1152      // KS + HSEL fused N
#define CHK   32        // scan chunk length

typedef unsigned short u16;
typedef __attribute__((ext_vector_type(8))) __bf16 bf16x8;
typedef __attribute__((ext_vector_type(4))) float  f32x4;

__device__ __forceinline__ u16 f2bf(float f) {
  union { float f; unsigned int u; } v; v.f = f;
  unsigned int u = v.u;
  return (u16)((u + 0x7fffu + ((u >> 16) & 1u)) >> 16);
}
__device__ __forceinline__ float bf2f(u16 h) {
  union { unsigned int u; float f; } v; v.u = ((unsigned int)h) << 16;
  return v.f;
}
__device__ __forceinline__ float sigm(float x)  { return 1.0f / (1.0f + __expf(-x)); }
__device__ __forceinline__ float tanhf2(float x){ return 1.0f - 2.0f / (1.0f + __expf(2.0f * x)); }

__device__ __forceinline__ void async_ld16(const void* g, void* l) {
  __builtin_amdgcn_global_load_lds(
      (const __attribute__((address_space(1))) unsigned int*)g,
      (__attribute__((address_space(3))) unsigned int*)l, 16, 0, 0);
}

__device__ __forceinline__ f32x4 mfma16(bf16x8 a, bf16x8 b, f32x4 c) {
  return __builtin_amdgcn_mfma_f32_16x16x32_bf16(a, b, c, 0, 0, 0);
}

// ---------------- all weight transposes in ONE kernel (worklist) ----------------
struct TJobs { const float* in[6]; u16* out[6]; };

__global__ void transpose_all(TJobs jobs) {
  // job tiles: base offsets in 32x32 tiles (see host)
  const int base[7] = {0, 4096, 4608, 6656, 10752, 14848, 18944};
  const int RR[6]  = {1024, 1024, 128, 1024, 1024, 4096};
  const int CC[6]  = {1024, 128, 4096, 1024, 4096, 1024};
  const int OR0[6] = {0, 1024, 0, 0, 0, 0};
  const int OBR[6] = {1152, 1152, 4096, 1024, 4096, 1024};
  int bid = blockIdx.x;
  int j = 0;
#pragma unroll
  for (int i = 1; i < 6; i++) if (bid >= base[i]) j = i;
  int R = RR[j], C = CC[j];
  int tiles_x = C >> 5;
  int per_z = tiles_x * (R >> 5);
  int local = bid - base[j];
  int z = local / per_z, rem = local % per_z;
  int c0 = (rem % tiles_x) * 32, r0 = (rem / tiles_x) * 32;
  const float* inb = jobs.in[j] + (size_t)z * R * C;
  u16* outb = jobs.out[j] + (size_t)z * OBR[j] * R;
  __shared__ u16 tile[32][33];
  int tx = threadIdx.x, ty = threadIdx.y;   // block (32,8)
#pragma unroll
  for (int i = 0; i < 4; i++) {
    int r = r0 + ty + i * 8;
    tile[ty + i * 8][tx] = f2bf(inb[(size_t)r * C + c0 + tx]);
  }
  __syncthreads();
#pragma unroll
  for (int i = 0; i < 4; i++) {
    int c = c0 + ty + i * 8;
    outb[(size_t)(OR0[j] + c) * R + r0 + tx] = tile[tx][ty + i * 8];
  }
}

// ---------------- routing ----------------
__global__ void routing_kernel(const int* __restrict__ token_ids,
                               int* __restrict__ perm, int* __restrict__ tpos,
                               int* __restrict__ goff) {
  __shared__ int cnt[256 * 8];
  __shared__ int btot[8];
  __shared__ int bbase[8];
  int t = threadIdx.x;
  int lc[8]; int myg[16];
#pragma unroll
  for (int j = 0; j < 8; j++) lc[j] = 0;
#pragma unroll
  for (int i = 0; i < 16; i++) {
    int tok = t * 16 + i;
    unsigned int h = (unsigned int)token_ids[tok];
    h ^= h >> 16; h *= 2246822507u; h ^= h >> 13; h *= 3266489909u; h ^= h >> 16;
    int route = (int)(h & 3u);
    int g = route * 2 + (tok >> 11);   // (expert, batch)
    myg[i] = g; lc[g]++;
  }
#pragma unroll
  for (int j = 0; j < 8; j++) cnt[t * 8 + j] = lc[j];
  __syncthreads();
  int wave = t >> 6, lane = t & 63;
  for (int j = wave * 2; j < wave * 2 + 2; j++) {
    int v0 = cnt[(4 * lane + 0) * 8 + j];
    int v1 = cnt[(4 * lane + 1) * 8 + j];
    int v2 = cnt[(4 * lane + 2) * 8 + j];
    int v3 = cnt[(4 * lane + 3) * 8 + j];
    int s = v0 + v1 + v2 + v3;
    int inc = s;
    for (int d = 1; d < 64; d <<= 1) {
      int o = __shfl_up(inc, d);
      if (lane >= d) inc += o;
    }
    int excl = inc - s;
    cnt[(4 * lane + 0) * 8 + j] = excl;
    cnt[(4 * lane + 1) * 8 + j] = excl + v0;
    cnt[(4 * lane + 2) * 8 + j] = excl + v0 + v1;
    cnt[(4 * lane + 3) * 8 + j] = excl + v0 + v1 + v2;
    if (lane == 63) btot[j] = inc;
  }
  __syncthreads();
  if (t == 0) {
    int run = 0;
    for (int j = 0; j < 8; j++) { bbase[j] = run; goff[j] = run; run += btot[j]; }
    goff[8] = run;
  }
  __syncthreads();
  int pos[8];
#pragma unroll
  for (int j = 0; j < 8; j++) pos[j] = bbase[j] + cnt[t * 8 + j];
#pragma unroll
  for (int i = 0; i < 16; i++) {
    int g = myg[i];
    int tok = t * 16 + i;
    perm[pos[g]] = tok;
    tpos[tok] = pos[g];
    pos[g]++;
  }
}

// ---------------- elementwise: (optional residual mix) + rmsnorm -> bf16 ----------------
template <bool MIX>
__global__ void ew_rms(const float* __restrict__ in, const float* __restrict__ in2,
                       const float* __restrict__ mix, float* __restrict__ mix_out,
                       const int* __restrict__ tpos, u16* __restrict__ nrm_out) {
  int row = blockIdx.x;
  int t = threadIdx.x;
  size_t base = (size_t)row * DIM + t * 4;
  float4 v;
  if (MIX) {
    float4 a = *(const float4*)(in + base);
    float4 b = *(const float4*)(in2 + base);
    float4 m0 = *(const float4*)(mix + t * 4);
    float4 m1 = *(const float4*)(mix + DIM + t * 4);
    v.x = m0.x * a.x + m1.x * b.x;
    v.y = m0.y * a.y + m1.y * b.y;
    v.z = m0.z * a.z + m1.z * b.z;
    v.w = m0.w * a.w + m1.w * b.w;
    *(float4*)(mix_out + base) = v;
  } else {
    v = *(const float4*)(in + base);
  }
  float ss = v.x * v.x + v.y * v.y + v.z * v.z + v.w * v.w;
#pragma unroll
  for (int d = 32; d >= 1; d >>= 1) ss += __shfl_xor(ss, d);
  __shared__ float red[4];
  int wave = t >> 6, lane = t & 63;
  if (lane == 0) red[wave] = ss;
  __syncthreads();
  float tot = red[0] + red[1] + red[2] + red[3];
  float sc = rsqrtf(tot * (1.0f / (float)DIM) + 1e-6f);
  ushort4 o;
  o.x = f2bf(v.x * sc); o.y = f2bf(v.y * sc); o.z = f2bf(v.z * sc); o.w = f2bf(v.w * sc);
  size_t obase = MIX ? ((size_t)tpos[row] * DIM + t * 4) : base;
  *(ushort4*)(nrm_out + obase) = o;
}

// ---------------- GEMM: TM x TN tile, BK=32, single-buffer 2-barrier loop ----------------
// (round-2 structure: best measured). 4 waves in 2x2; wave tile (ATM*16) x (ATN*16).
// LDS phys chunk p of row r holds logical chunk p ^ ((r>>1)&3)  (conflict-free, measured 0).
// AMODE: 1 = A rows compact (grouped via goff), 2 = dense M
// EPI: 2 bf16 | 3 ssm residual scatter via perm | 4 relu^2 bf16 | 5 mlp residual
//      | 6 fused: col<KS -> bf16 u, col>=KS -> silu bf16 sh
template <int TM, int TN, int AMODE, int EPI>
__global__ __launch_bounds__(256, 4)
void gemm_t(const u16* __restrict__ A, const u16* __restrict__ Bt,
            int K, int Ntot, int Mfixed,
            const int* __restrict__ perm, const int* __restrict__ goff,
            float* __restrict__ outf, u16* __restrict__ outb, u16* __restrict__ outb2,
            const float* __restrict__ xres, const float* __restrict__ svec) {
  constexpr int BK = 32;
  constexpr int CH_A = TM * 4;            // 16B chunks per BK-slab of A
  constexpr int CH_B = TN * 4;
  constexpr int ITERS = (CH_A + CH_B) / 256;
  constexpr int ATM = TM / 32;            // wave m-extent = ATM*16
  constexpr int ATN = TN / 32;
  static_assert(CH_A % 256 == 0, "A/B staging boundary must align to wave iters");

  int e = blockIdx.z;
  int row_start, row_end;
  if (AMODE == 2) { row_start = 0; row_end = Mfixed; }
  else { row_start = goff[2 * e]; row_end = goff[2 * e + 2]; }
  int m0 = row_start + blockIdx.x * TM;
  if (m0 >= row_end) return;
  int n0 = blockIdx.y * TN;
  const u16* Bte = Bt + (size_t)e * Ntot * K;

  __shared__ __align__(16) u16 As[TM * BK];
  __shared__ __align__(16) u16 Bs[TN * BK];

  int tid = threadIdx.x;
  int wave = tid >> 6, lane = tid & 63;
  int wm = wave & 1, wn = wave >> 1;
  int lrow = lane & 15, lq = lane >> 4;

  const u16* gptr[ITERS];
#pragma unroll
  for (int i = 0; i < ITERS; i++) {
    int s = tid + i * 256;
    if (i * 256 < CH_A) {              // stages A
      int r = s >> 2;
      int c = (s & 3) ^ ((r >> 1) & 3);
      int gr = m0 + r;
      int cl = (AMODE == 2) ? gr : (gr < row_end ? gr : row_end - 1);
      gptr[i] = A + (size_t)cl * K + c * 8;
    } else {                           // stages B
      int s2 = s - CH_A;
      int r = s2 >> 2;
      int c = (s2 & 3) ^ ((r >> 1) & 3);
      gptr[i] = Bte + (size_t)(n0 + r) * K + c * 8;
    }
  }

  f32x4 acc[ATM][ATN];
#pragma unroll
  for (int i = 0; i < ATM; i++)
#pragma unroll
    for (int j = 0; j < ATN; j++) acc[i][j] = (f32x4){0.f, 0.f, 0.f, 0.f};

  int aoff[ATM], boff[ATN];
#pragma unroll
  for (int tm = 0; tm < ATM; tm++) {
    int r = wm * (ATM * 16) + tm * 16 + lrow;
    aoff[tm] = r * BK + (lq ^ ((r >> 1) & 3)) * 8;
  }
#pragma unroll
  for (int tn = 0; tn < ATN; tn++) {
    int r = wn * (ATN * 16) + tn * 16 + lrow;
    boff[tn] = r * BK + (lq ^ ((r >> 1) & 3)) * 8;
  }

  for (int k0 = 0; k0 < K; k0 += BK) {
    __syncthreads();
#pragma unroll
    for (int i = 0; i < ITERS; i++) {
      if (i * 256 < CH_A)
        async_ld16(gptr[i] + k0, &As[(size_t)(i * 256 + wave * 64) * 8]);
      else
        async_ld16(gptr[i] + k0, &Bs[(size_t)(i * 256 - CH_A + wave * 64) * 8]);
    }
    __syncthreads();
    bf16x8 af[ATM], bb[ATN];
#pragma unroll
    for (int tm = 0; tm < ATM; tm++) af[tm] = *(const bf16x8*)&As[aoff[tm]];
#pragma unroll
    for (int tn = 0; tn < ATN; tn++) bb[tn] = *(const bf16x8*)&Bs[boff[tn]];
#pragma unroll
    for (int tm = 0; tm < ATM; tm++)
#pragma unroll
      for (int tn = 0; tn < ATN; tn++)
        acc[tm][tn] = mfma16(af[tm], bb[tn], acc[tm][tn]);
  }

  // epilogue: C/D layout col = lane&15, row = (lane>>4)*4 + reg
#pragma unroll
  for (int tm = 0; tm < ATM; tm++) {
    int rowb = m0 + wm * (ATM * 16) + tm * 16 + lq * 4;
#pragma unroll
    for (int tn = 0; tn < ATN; tn++) {
      int col = n0 + wn * (ATN * 16) + tn * 16 + lrow;
#pragma unroll
      for (int r = 0; r < 4; r++) {
        int row = rowb + r;
        if (AMODE != 2 && row >= row_end) continue;
        float v = acc[tm][tn][r];
        if (EPI == 2) {
          outb[(size_t)row * Ntot + col] = f2bf(v);
        } else if (EPI == 3) {
          int tok = perm[row];
          size_t o = (size_t)tok * DIM + col;
          outf[o] = xres[o] + svec[col] * v;
        } else if (EPI == 4) {
          float t2 = fmaxf(v, 0.f);
          outb[(size_t)row * Ntot + col] = f2bf(t2 * t2);
        } else if (EPI == 5) {
          size_t o = (size_t)row * DIM + col;
          outf[o] = xres[o] + svec[col] * v;
        } else {  // EPI 6: fused bf16 u | silu(sel_in)
          if (col < KS) outb[(size_t)row * KS + col] = f2bf(v);
          else outb2[(size_t)row * HSEL + (col - KS)] = f2bf(v * sigm(v));
        }
      }
    }
  }
}

// ---------------- chunked linear scan: h = a*h + b*u  (u now bf16) ----------------
__global__ void scan_p1(const u16* __restrict__ u, const u16* __restrict__ sel,
                        const int* __restrict__ goff,
                        float* __restrict__ P, float* __restrict__ S) {
  int g = blockIdx.y;
  int beg = goff[g], end = goff[g + 1];
  int i0 = beg + blockIdx.x * CHK;
  if (i0 >= end) return;
  int ie = i0 + CHK < end ? i0 + CHK : end;
  int k0 = threadIdx.x * 4;
  float h0 = 0, h1 = 0, h2 = 0, h3 = 0;
  float p0 = 1, p1 = 1, p2 = 1, p3 = 1;
  for (int i = i0; i < ie; ++i) {
    size_t sb = (size_t)i * 4096 + k0;
    ushort4 uv = *(const ushort4*)(u + (size_t)i * KS + k0);
    ushort4 av = *(const ushort4*)(sel + sb);
    ushort4 bv = *(const ushort4*)(sel + sb + 1024);
    float u0 = bf2f(uv.x), u1 = bf2f(uv.y), u2 = bf2f(uv.z), u3 = bf2f(uv.w);
    float a0 = sigm(bf2f(av.x)), a1 = sigm(bf2f(av.y));
    float a2 = sigm(bf2f(av.z)), a3 = sigm(bf2f(av.w));
    float b0 = tanhf2(bf2f(bv.x)), b1 = tanhf2(bf2f(bv.y));
    float b2 = tanhf2(bf2f(bv.z)), b3 = tanhf2(bf2f(bv.w));
    h0 = a0 * h0 + b0 * u0; p0 *= a0;
    h1 = a1 * h1 + b1 * u1; p1 *= a1;
    h2 = a2 * h2 + b2 * u2; p2 *= a2;
    h3 = a3 * h3 + b3 * u3; p3 *= a3;
  }
  size_t ob = ((size_t)g * 128 + blockIdx.x) * KS + k0;
  *(float4*)(P + ob) = make_float4(p0, p1, p2, p3);
  *(float4*)(S + ob) = make_float4(h0, h1, h2, h3);
}

__global__ void scan_p2(const float* __restrict__ P, const float* __restrict__ S,
                        const int* __restrict__ goff, float* __restrict__ C) {
  int g = blockIdx.x;
  int k0 = blockIdx.y * 256 + threadIdx.x * 4;
  int beg = goff[g], end = goff[g + 1];
  int nch = (end - beg + CHK - 1) / CHK;
  float c0 = 0, c1 = 0, c2 = 0, c3 = 0;
#pragma unroll 4
  for (int ch = 0; ch < nch; ++ch) {
    size_t ob = ((size_t)g * 128 + ch) * KS + k0;
    float4 pv = *(const float4*)(P + ob);
    float4 sv = *(const float4*)(S + ob);
    *(float4*)(C + ob) = make_float4(c0, c1, c2, c3);
    c0 = pv.x * c0 + sv.x;
    c1 = pv.y * c1 + sv.y;
    c2 = pv.z * c2 + sv.z;
    c3 = pv.w * c3 + sv.w;
  }
}

__global__ void scan_p3(const u16* __restrict__ u, const u16* __restrict__ sel,
                        const int* __restrict__ goff, const float* __restrict__ C,
                        const float* __restrict__ dpar, u16* __restrict__ yst) {
  int g = blockIdx.y;
  int e = g >> 1;
  int beg = goff[g], end = goff[g + 1];
  int i0 = beg + blockIdx.x * CHK;
  if (i0 >= end) return;
  int ie = i0 + CHK < end ? i0 + CHK : end;
  int k0 = threadIdx.x * 4;
  size_t ob = ((size_t)g * 128 + blockIdx.x) * KS + k0;
  float4 hv = *(const float4*)(C + ob);
  float4 dv = *(const float4*)(dpar + (size_t)e * KS + k0);
  float h0 = hv.x, h1 = hv.y, h2 = hv.z, h3 = hv.w;
  for (int i = i0; i < ie; ++i) {
    size_t sb = (size_t)i * 4096 + k0;
    ushort4 uv = *(const ushort4*)(u + (size_t)i * KS + k0);
    ushort4 av = *(const ushort4*)(sel + sb);
    ushort4 bv = *(const ushort4*)(sel + sb + 1024);
    ushort4 cv = *(const ushort4*)(sel + sb + 2048);
    ushort4 gv = *(const ushort4*)(sel + sb + 3072);
    float u0 = bf2f(uv.x), u1 = bf2f(uv.y), u2 = bf2f(uv.z), u3 = bf2f(uv.w);
    float a0 = sigm(bf2f(av.x)), a1 = sigm(bf2f(av.y));
    float a2 = sigm(bf2f(av.z)), a3 = sigm(bf2f(av.w));
    float b0 = tanhf2(bf2f(bv.x)), b1 = tanhf2(bf2f(bv.y));
    float b2 = tanhf2(bf2f(bv.z)), b3 = tanhf2(bf2f(bv.w));
    float q0 = tanhf2(bf2f(cv.x)), q1 = tanhf2(bf2f(cv.y));
    float q2 = tanhf2(bf2f(cv.z)), q3 = tanhf2(bf2f(cv.w));
    float g0 = sigm(bf2f(gv.x)), g1 = sigm(bf2f(gv.y));
    float g2 = sigm(bf2f(gv.z)), g3 = sigm(bf2f(gv.w));
    h0 = a0 * h0 + b0 * u0;
    h1 = a1 * h1 + b1 * u1;
    h2 = a2 * h2 + b2 * u2;
    h3 = a3 * h3 + b3 * u3;
    ushort4 o;
    o.x = f2bf(q0 * h0 + dv.x * g0 * u0);
    o.y = f2bf(q1 * h1 + dv.y * g1 * u1);
    o.z = f2bf(q2 * h2 + dv.z * g2 * u2);
    o.w = f2bf(q3 * h3 + dv.w * g3 * u3);
    *(ushort4*)(yst + (size_t)i * KS + k0) = o;
  }
}

// ---------------- host launch ----------------
extern "C" void kernel_launch(void* const* d_in, const int* in_sizes, int n_in,
                              void* d_out, int out_size, void* d_ws, size_t ws_size,
                              hipStream_t stream) {
  const float* x      = (const float*)d_in[0];
  const float* x0     = (const float*)d_in[1];
  const float* W_in   = (const float*)d_in[2];
  const float* W_seli = (const float*)d_in[3];
  const float* W_selo = (const float*)d_in[4];
  const float* W_out  = (const float*)d_in[5];
  const float* d_par  = (const float*)d_in[6];
  const float* ssm_s  = (const float*)d_in[7];
  const float* mlp_s  = (const float*)d_in[8];
  const float* rmix   = (const float*)d_in[9];
  const float* W_fc   = (const float*)d_in[10];
  const float* W_proj = (const float*)d_in[11];
  const int*   tok    = (const int*)d_in[12];
  float* out = (float*)d_out;

  char* p = (char*)d_ws;
  u16* wt_cat  = (u16*)p; p += (size_t)NE * NCAT * DIM * 2;    // [e][1152][1024]
  u16* wt_selo = (u16*)p; p += (size_t)NE * 4 * KS * HSEL * 2; // [e][4096][128]
  u16* wt_out  = (u16*)p; p += (size_t)NE * DIM * KS * 2;      // [e][1024][1024]
  u16* wt_fc   = (u16*)p; p += (size_t)DFF * DIM * 2;          // [4096][1024]
  u16* wt_pr   = (u16*)p; p += (size_t)DIM * DFF * 2;          // [1024][4096]
  u16* xs      = (u16*)p; p += (size_t)T_TOK * DIM * 2;        // permuted order
  u16* sh      = (u16*)p; p += (size_t)T_TOK * HSEL * 2;
  u16* sel     = (u16*)p; p += (size_t)T_TOK * 4 * KS * 2;
  u16* yst     = (u16*)p; p += (size_t)T_TOK * KS * 2;
  u16* xn2     = (u16*)p; p += (size_t)T_TOK * DIM * 2;
  u16* hmid    = (u16*)p; p += (size_t)T_TOK * DFF * 2;
  u16* ubuf    = (u16*)p; p += (size_t)T_TOK * KS * 2;         // bf16 u
  float* xmix = (float*)p; p += (size_t)T_TOK * DIM * 4;
  float* x2   = (float*)p; p += (size_t)T_TOK * DIM * 4;
  float* Pbuf = (float*)p; p += (size_t)8 * 128 * KS * 4;
  float* Sbuf = (float*)p; p += (size_t)8 * 128 * KS * 4;
  float* Cbuf = (float*)p; p += (size_t)8 * 128 * KS * 4;
  int* perm = (int*)p; p += (size_t)T_TOK * 4;
  int* tpos = (int*)p; p += (size_t)T_TOK * 4;
  int* goff = (int*)p; p += 16 * 4;

  // all 6 weight transposes in one launch
  TJobs tj;
  tj.in[0] = W_in;   tj.out[0] = wt_cat;
  tj.in[1] = W_seli; tj.out[1] = wt_cat;
  tj.in[2] = W_selo; tj.out[2] = wt_selo;
  tj.in[3] = W_out;  tj.out[3] = wt_out;
  tj.in[4] = W_fc;   tj.out[4] = wt_fc;
  tj.in[5] = W_proj; tj.out[5] = wt_pr;
  transpose_all<<<18944, dim3(32, 8, 1), 0, stream>>>(tj);

  routing_kernel<<<1, 256, 0, stream>>>(tok, perm, tpos, goff);
  ew_rms<true><<<T_TOK, 256, 0, stream>>>(x, x0, rmix, xmix, tpos, xs);

  // fused u + silu(sel_in): grouped, N=1152, TM=64/TN=64 -> ~1152 active blocks
  gemm_t<64, 64, 1, 6><<<dim3(64, NCAT / 64, NE), 256, 0, stream>>>(
      xs, wt_cat, DIM, NCAT, 0, perm, goff, nullptr, ubuf, sh, nullptr, nullptr);
  // sel_out: grouped, N=4096, K=128 -> ~2048 active blocks
  gemm_t<64, 128, 1, 2><<<dim3(64, 32, NE), 256, 0, stream>>>(
      sh, wt_selo, HSEL, 4 * KS, 0, perm, goff, nullptr, sel, nullptr, nullptr, nullptr);
  // recurrence
  scan_p1<<<dim3(128, 8), 256, 0, stream>>>(ubuf, sel, goff, Pbuf, Sbuf);
  scan_p2<<<dim3(8, 4), 64, 0, stream>>>(Pbuf, Sbuf, goff, Cbuf);
  scan_p3<<<dim3(128, 8), 256, 0, stream>>>(ubuf, sel, goff, Cbuf, d_par, yst);
  // routed out-proj + residual scatter: ~1024 active blocks
  gemm_t<64, 64, 1, 3><<<dim3(64, 16, NE), 256, 0, stream>>>(
      yst, wt_out, KS, DIM, 0, perm, goff, x2, nullptr, nullptr, xmix, ssm_s);
  // MLP
  ew_rms<false><<<T_TOK, 256, 0, stream>>>(x2, nullptr, nullptr, nullptr, nullptr, xn2);
  gemm_t<64, 128, 2, 4><<<dim3(64, 32, 1), 256, 0, stream>>>(
      xn2, wt_fc, DIM, DFF, T_TOK, nullptr, nullptr, nullptr, hmid, nullptr, nullptr, nullptr);
  gemm_t<64, 64, 2, 5><<<dim3(64, 16, 1), 256, 0, stream>>>(
      hmid, wt_pr, DFF, DIM, T_TOK, nullptr, nullptr, out, nullptr, nullptr, x2, mlp_s);
}

// Round 6
// 461.688 us; speedup vs baseline: 1.2867x; 1.1272x over previous
//
#include <hip/hip_runtime.h>

// ---------------- constants ----------------
#define T_TOK 4096      // B*S
#define DIM   1024
#define KS    1024      // STATE
#define HSEL  128
#define NE    4
#define DFF   4096
#define NCAT  1152      // KS + HSEL fused N
#define CHK   8         // scan chunk length (8 => ~512 active blocks, 2/CU)
#define MAXCH 256       // max chunks per group (group <= 2048 tokens)

typedef unsigned short u16;
typedef __attribute__((ext_vector_type(8))) __bf16 bf16x8;
typedef __attribute__((ext_vector_type(4))) float  f32x4;

__device__ __forceinline__ u16 f2bf(float f) {
  union { float f; unsigned int u; } v; v.f = f;
  unsigned int u = v.u;
  return (u16)((u + 0x7fffu + ((u >> 16) & 1u)) >> 16);
}
__device__ __forceinline__ float bf2f(u16 h) {
  union { unsigned int u; float f; } v; v.u = ((unsigned int)h) << 16;
  return v.f;
}
__device__ __forceinline__ float sigm(float x)  { return 1.0f / (1.0f + __expf(-x)); }
__device__ __forceinline__ float tanhf2(float x){ return 1.0f - 2.0f / (1.0f + __expf(2.0f * x)); }

__device__ __forceinline__ void async_ld16(const void* g, void* l) {
  __builtin_amdgcn_global_load_lds(
      (const __attribute__((address_space(1))) unsigned int*)g,
      (__attribute__((address_space(3))) unsigned int*)l, 16, 0, 0);
}

__device__ __forceinline__ f32x4 mfma16(bf16x8 a, bf16x8 b, f32x4 c) {
  return __builtin_amdgcn_mfma_f32_16x16x32_bf16(a, b, c, 0, 0, 0);
}

// ---------------- all weight transposes in ONE kernel (worklist) ----------------
struct TJobs { const float* in[6]; u16* out[6]; };

__global__ void transpose_all(TJobs jobs) {
  const int base[7] = {0, 4096, 4608, 6656, 10752, 14848, 18944};
  const int RR[6]  = {1024, 1024, 128, 1024, 1024, 4096};
  const int CC[6]  = {1024, 128, 4096, 1024, 4096, 1024};
  const int OR0[6] = {0, 1024, 0, 0, 0, 0};
  const int OBR[6] = {1152, 1152, 4096, 1024, 4096, 1024};
  int bid = blockIdx.x;
  int j = 0;
#pragma unroll
  for (int i = 1; i < 6; i++) if (bid >= base[i]) j = i;
  int R = RR[j], C = CC[j];
  int tiles_x = C >> 5;
  int per_z = tiles_x * (R >> 5);
  int local = bid - base[j];
  int z = local / per_z, rem = local % per_z;
  int c0 = (rem % tiles_x) * 32, r0 = (rem / tiles_x) * 32;
  const float* inb = jobs.in[j] + (size_t)z * R * C;
  u16* outb = jobs.out[j] + (size_t)z * OBR[j] * R;
  __shared__ u16 tile[32][33];
  int tx = threadIdx.x, ty = threadIdx.y;   // block (32,8)
#pragma unroll
  for (int i = 0; i < 4; i++) {
    int r = r0 + ty + i * 8;
    tile[ty + i * 8][tx] = f2bf(inb[(size_t)r * C + c0 + tx]);
  }
  __syncthreads();
#pragma unroll
  for (int i = 0; i < 4; i++) {
    int c = c0 + ty + i * 8;
    outb[(size_t)(OR0[j] + c) * R + r0 + tx] = tile[tx][ty + i * 8];
  }
}

// ---------------- routing ----------------
__global__ void routing_kernel(const int* __restrict__ token_ids,
                               int* __restrict__ perm, int* __restrict__ tpos,
                               int* __restrict__ goff) {
  __shared__ int cnt[256 * 8];
  __shared__ int btot[8];
  __shared__ int bbase[8];
  int t = threadIdx.x;
  int lc[8]; int myg[16];
#pragma unroll
  for (int j = 0; j < 8; j++) lc[j] = 0;
#pragma unroll
  for (int i = 0; i < 16; i++) {
    int tok = t * 16 + i;
    unsigned int h = (unsigned int)token_ids[tok];
    h ^= h >> 16; h *= 2246822507u; h ^= h >> 13; h *= 3266489909u; h ^= h >> 16;
    int route = (int)(h & 3u);
    int g = route * 2 + (tok >> 11);   // (expert, batch)
    myg[i] = g; lc[g]++;
  }
#pragma unroll
  for (int j = 0; j < 8; j++) cnt[t * 8 + j] = lc[j];
  __syncthreads();
  int wave = t >> 6, lane = t & 63;
  for (int j = wave * 2; j < wave * 2 + 2; j++) {
    int v0 = cnt[(4 * lane + 0) * 8 + j];
    int v1 = cnt[(4 * lane + 1) * 8 + j];
    int v2 = cnt[(4 * lane + 2) * 8 + j];
    int v3 = cnt[(4 * lane + 3) * 8 + j];
    int s = v0 + v1 + v2 + v3;
    int inc = s;
    for (int d = 1; d < 64; d <<= 1) {
      int o = __shfl_up(inc, d);
      if (lane >= d) inc += o;
    }
    int excl = inc - s;
    cnt[(4 * lane + 0) * 8 + j] = excl;
    cnt[(4 * lane + 1) * 8 + j] = excl + v0;
    cnt[(4 * lane + 2) * 8 + j] = excl + v0 + v1;
    cnt[(4 * lane + 3) * 8 + j] = excl + v0 + v1 + v2;
    if (lane == 63) btot[j] = inc;
  }
  __syncthreads();
  if (t == 0) {
    int run = 0;
    for (int j = 0; j < 8; j++) { bbase[j] = run; goff[j] = run; run += btot[j]; }
    goff[8] = run;
  }
  __syncthreads();
  int pos[8];
#pragma unroll
  for (int j = 0; j < 8; j++) pos[j] = bbase[j] + cnt[t * 8 + j];
#pragma unroll
  for (int i = 0; i < 16; i++) {
    int g = myg[i];
    int tok = t * 16 + i;
    perm[pos[g]] = tok;
    tpos[tok] = pos[g];
    pos[g]++;
  }
}

// ---------------- elementwise: (optional residual mix) + rmsnorm -> bf16 ----------------
template <bool MIX>
__global__ void ew_rms(const float* __restrict__ in, const float* __restrict__ in2,
                       const float* __restrict__ mix, float* __restrict__ mix_out,
                       const int* __restrict__ tpos, u16* __restrict__ nrm_out) {
  int row = blockIdx.x;
  int t = threadIdx.x;
  size_t base = (size_t)row * DIM + t * 4;
  float4 v;
  if (MIX) {
    float4 a = *(const float4*)(in + base);
    float4 b = *(const float4*)(in2 + base);
    float4 m0 = *(const float4*)(mix + t * 4);
    float4 m1 = *(const float4*)(mix + DIM + t * 4);
    v.x = m0.x * a.x + m1.x * b.x;
    v.y = m0.y * a.y + m1.y * b.y;
    v.z = m0.z * a.z + m1.z * b.z;
    v.w = m0.w * a.w + m1.w * b.w;
    *(float4*)(mix_out + base) = v;
  } else {
    v = *(const float4*)(in + base);
  }
  float ss = v.x * v.x + v.y * v.y + v.z * v.z + v.w * v.w;
#pragma unroll
  for (int d = 32; d >= 1; d >>= 1) ss += __shfl_xor(ss, d);
  __shared__ float red[4];
  int wave = t >> 6, lane = t & 63;
  if (lane == 0) red[wave] = ss;
  __syncthreads();
  float tot = red[0] + red[1] + red[2] + red[3];
  float sc = rsqrtf(tot * (1.0f / (float)DIM) + 1e-6f);
  ushort4 o;
  o.x = f2bf(v.x * sc); o.y = f2bf(v.y * sc); o.z = f2bf(v.z * sc); o.w = f2bf(v.w * sc);
  size_t obase = MIX ? ((size_t)tpos[row] * DIM + t * 4) : base;
  *(ushort4*)(nrm_out + obase) = o;
}

// ---------------- GEMM: TM x TN tile, BK=32, single-buffer 2-barrier loop ----------------
template <int TM, int TN, int AMODE, int EPI>
__global__ __launch_bounds__(256, 4)
void gemm_t(const u16* __restrict__ A, const u16* __restrict__ Bt,
            int K, int Ntot, int Mfixed,
            const int* __restrict__ perm, const int* __restrict__ goff,
            float* __restrict__ outf, u16* __restrict__ outb, u16* __restrict__ outb2,
            const float* __restrict__ xres, const float* __restrict__ svec) {
  constexpr int BK = 32;
  constexpr int CH_A = TM * 4;
  constexpr int CH_B = TN * 4;
  constexpr int ITERS = (CH_A + CH_B) / 256;
  constexpr int ATM = TM / 32;
  constexpr int ATN = TN / 32;
  static_assert(CH_A % 256 == 0, "A/B staging boundary must align to wave iters");

  int e = blockIdx.z;
  int row_start, row_end;
  if (AMODE == 2) { row_start = 0; row_end = Mfixed; }
  else { row_start = goff[2 * e]; row_end = goff[2 * e + 2]; }
  int m0 = row_start + blockIdx.x * TM;
  if (m0 >= row_end) return;
  int n0 = blockIdx.y * TN;
  const u16* Bte = Bt + (size_t)e * Ntot * K;

  __shared__ __align__(16) u16 As[TM * BK];
  __shared__ __align__(16) u16 Bs[TN * BK];

  int tid = threadIdx.x;
  int wave = tid >> 6, lane = tid & 63;
  int wm = wave & 1, wn = wave >> 1;
  int lrow = lane & 15, lq = lane >> 4;

  const u16* gptr[ITERS];
#pragma unroll
  for (int i = 0; i < ITERS; i++) {
    int s = tid + i * 256;
    if (i * 256 < CH_A) {
      int r = s >> 2;
      int c = (s & 3) ^ ((r >> 1) & 3);
      int gr = m0 + r;
      int cl = (AMODE == 2) ? gr : (gr < row_end ? gr : row_end - 1);
      gptr[i] = A + (size_t)cl * K + c * 8;
    } else {
      int s2 = s - CH_A;
      int r = s2 >> 2;
      int c = (s2 & 3) ^ ((r >> 1) & 3);
      gptr[i] = Bte + (size_t)(n0 + r) * K + c * 8;
    }
  }

  f32x4 acc[ATM][ATN];
#pragma unroll
  for (int i = 0; i < ATM; i++)
#pragma unroll
    for (int j = 0; j < ATN; j++) acc[i][j] = (f32x4){0.f, 0.f, 0.f, 0.f};

  int aoff[ATM], boff[ATN];
#pragma unroll
  for (int tm = 0; tm < ATM; tm++) {
    int r = wm * (ATM * 16) + tm * 16 + lrow;
    aoff[tm] = r * BK + (lq ^ ((r >> 1) & 3)) * 8;
  }
#pragma unroll
  for (int tn = 0; tn < ATN; tn++) {
    int r = wn * (ATN * 16) + tn * 16 + lrow;
    boff[tn] = r * BK + (lq ^ ((r >> 1) & 3)) * 8;
  }

  for (int k0 = 0; k0 < K; k0 += BK) {
    __syncthreads();
#pragma unroll
    for (int i = 0; i < ITERS; i++) {
      if (i * 256 < CH_A)
        async_ld16(gptr[i] + k0, &As[(size_t)(i * 256 + wave * 64) * 8]);
      else
        async_ld16(gptr[i] + k0, &Bs[(size_t)(i * 256 - CH_A + wave * 64) * 8]);
    }
    __syncthreads();
    bf16x8 af[ATM], bb[ATN];
#pragma unroll
    for (int tm = 0; tm < ATM; tm++) af[tm] = *(const bf16x8*)&As[aoff[tm]];
#pragma unroll
    for (int tn = 0; tn < ATN; tn++) bb[tn] = *(const bf16x8*)&Bs[boff[tn]];
#pragma unroll
    for (int tm = 0; tm < ATM; tm++)
#pragma unroll
      for (int tn = 0; tn < ATN; tn++)
        acc[tm][tn] = mfma16(af[tm], bb[tn], acc[tm][tn]);
  }

  // epilogue: C/D layout col = lane&15, row = (lane>>4)*4 + reg
#pragma unroll
  for (int tm = 0; tm < ATM; tm++) {
    int rowb = m0 + wm * (ATM * 16) + tm * 16 + lq * 4;
#pragma unroll
    for (int tn = 0; tn < ATN; tn++) {
      int col = n0 + wn * (ATN * 16) + tn * 16 + lrow;
#pragma unroll
      for (int r = 0; r < 4; r++) {
        int row = rowb + r;
        if (AMODE != 2 && row >= row_end) continue;
        float v = acc[tm][tn][r];
        if (EPI == 2) {
          outb[(size_t)row * Ntot + col] = f2bf(v);
        } else if (EPI == 3) {
          int tok = perm[row];
          size_t o = (size_t)tok * DIM + col;
          outf[o] = xres[o] + svec[col] * v;
        } else if (EPI == 4) {
          float t2 = fmaxf(v, 0.f);
          outb[(size_t)row * Ntot + col] = f2bf(t2 * t2);
        } else if (EPI == 5) {
          size_t o = (size_t)row * DIM + col;
          outf[o] = xres[o] + svec[col] * v;
        } else {  // EPI 6: fused bf16 u | silu(sel_in)
          if (col < KS) outb[(size_t)row * KS + col] = f2bf(v);
          else outb2[(size_t)row * HSEL + (col - KS)] = f2bf(v * sigm(v));
        }
      }
    }
  }
}

// ---------------- chunked linear scan: h = a*h + b*u ----------------
// CHK=8, fully-unrolled full-chunk fast path (exposes ~24-40 outstanding loads).
__global__ void scan_p1(const u16* __restrict__ u, const u16* __restrict__ sel,
                        const int* __restrict__ goff,
                        float* __restrict__ P, float* __restrict__ S) {
  int g = blockIdx.y;
  int beg = goff[g], end = goff[g + 1];
  int i0 = beg + blockIdx.x * CHK;
  if (i0 >= end) return;
  int k0 = threadIdx.x * 4;
  float h0 = 0, h1 = 0, h2 = 0, h3 = 0;
  float p0 = 1, p1 = 1, p2 = 1, p3 = 1;
#define P1_BODY(i)                                                        \
  {                                                                       \
    size_t sb = (size_t)(i) * 4096 + k0;                                  \
    ushort4 uv = *(const ushort4*)(u + (size_t)(i) * KS + k0);            \
    ushort4 av = *(const ushort4*)(sel + sb);                             \
    ushort4 bv = *(const ushort4*)(sel + sb + 1024);                      \
    float a0 = sigm(bf2f(av.x)), a1 = sigm(bf2f(av.y));                   \
    float a2 = sigm(bf2f(av.z)), a3 = sigm(bf2f(av.w));                   \
    float b0 = tanhf2(bf2f(bv.x)), b1 = tanhf2(bf2f(bv.y));               \
    float b2 = tanhf2(bf2f(bv.z)), b3 = tanhf2(bf2f(bv.w));               \
    h0 = a0 * h0 + b0 * bf2f(uv.x); p0 *= a0;                             \
    h1 = a1 * h1 + b1 * bf2f(uv.y); p1 *= a1;                             \
    h2 = a2 * h2 + b2 * bf2f(uv.z); p2 *= a2;                             \
    h3 = a3 * h3 + b3 * bf2f(uv.w); p3 *= a3;                             \
  }
  if (i0 + CHK <= end) {
#pragma unroll
    for (int j = 0; j < CHK; ++j) P1_BODY(i0 + j)
  } else {
    for (int i = i0; i < end; ++i) P1_BODY(i)
  }
#undef P1_BODY
  size_t ob = ((size_t)g * MAXCH + blockIdx.x) * KS + k0;
  *(float4*)(P + ob) = make_float4(p0, p1, p2, p3);
  *(float4*)(S + ob) = make_float4(h0, h1, h2, h3);
}

__global__ void scan_p2(const float* __restrict__ P, const float* __restrict__ S,
                        const int* __restrict__ goff, float* __restrict__ C) {
  int g = blockIdx.x;
  int k0 = blockIdx.y * 256 + threadIdx.x * 4;
  int beg = goff[g], end = goff[g + 1];
  int nch = (end - beg + CHK - 1) / CHK;
  float c0 = 0, c1 = 0, c2 = 0, c3 = 0;
#pragma unroll 4
  for (int ch = 0; ch < nch; ++ch) {
    size_t ob = ((size_t)g * MAXCH + ch) * KS + k0;
    float4 pv = *(const float4*)(P + ob);
    float4 sv = *(const float4*)(S + ob);
    *(float4*)(C + ob) = make_float4(c0, c1, c2, c3);
    c0 = pv.x * c0 + sv.x;
    c1 = pv.y * c1 + sv.y;
    c2 = pv.z * c2 + sv.z;
    c3 = pv.w * c3 + sv.w;
  }
}

__global__ void scan_p3(const u16* __restrict__ u, const u16* __restrict__ sel,
                        const int* __restrict__ goff, const float* __restrict__ C,
                        const float* __restrict__ dpar, u16* __restrict__ yst) {
  int g = blockIdx.y;
  int e = g >> 1;
  int beg = goff[g], end = goff[g + 1];
  int i0 = beg + blockIdx.x * CHK;
  if (i0 >= end) return;
  int k0 = threadIdx.x * 4;
  size_t ob = ((size_t)g * MAXCH + blockIdx.x) * KS + k0;
  float4 hv = *(const float4*)(C + ob);
  float4 dv = *(const float4*)(dpar + (size_t)e * KS + k0);
  float h0 = hv.x, h1 = hv.y, h2 = hv.z, h3 = hv.w;
#define P3_BODY(i)                                                        \
  {                                                                       \
    size_t sb = (size_t)(i) * 4096 + k0;                                  \
    ushort4 uv = *(const ushort4*)(u + (size_t)(i) * KS + k0);            \
    ushort4 av = *(const ushort4*)(sel + sb);                             \
    ushort4 bv = *(const ushort4*)(sel + sb + 1024);                      \
    ushort4 cv = *(const ushort4*)(sel + sb + 2048);                      \
    ushort4 gv = *(const ushort4*)(sel + sb + 3072);                      \
    float u0 = bf2f(uv.x), u1 = bf2f(uv.y), u2 = bf2f(uv.z), u3 = bf2f(uv.w); \
    float a0 = sigm(bf2f(av.x)), a1 = sigm(bf2f(av.y));                   \
    float a2 = sigm(bf2f(av.z)), a3 = sigm(bf2f(av.w));                   \
    float b0 = tanhf2(bf2f(bv.x)), b1 = tanhf2(bf2f(bv.y));               \
    float b2 = tanhf2(bf2f(bv.z)), b3 = tanhf2(bf2f(bv.w));               \
    float q0 = tanhf2(bf2f(cv.x)), q1 = tanhf2(bf2f(cv.y));               \
    float q2 = tanhf2(bf2f(cv.z)), q3 = tanhf2(bf2f(cv.w));               \
    float g0 = sigm(bf2f(gv.x)), g1 = sigm(bf2f(gv.y));                   \
    float g2 = sigm(bf2f(gv.z)), g3 = sigm(bf2f(gv.w));                   \
    h0 = a0 * h0 + b0 * u0;                                               \
    h1 = a1 * h1 + b1 * u1;                                               \
    h2 = a2 * h2 + b2 * u2;                                               \
    h3 = a3 * h3 + b3 * u3;                                               \
    ushort4 o;                                                            \
    o.x = f2bf(q0 * h0 + dv.x * g0 * u0);                                 \
    o.y = f2bf(q1 * h1 + dv.y * g1 * u1);                                 \
    o.z = f2bf(q2 * h2 + dv.z * g2 * u2);                                 \
    o.w = f2bf(q3 * h3 + dv.w * g3 * u3);                                 \
    *(ushort4*)(yst + (size_t)(i) * KS + k0) = o;                         \
  }
  if (i0 + CHK <= end) {
#pragma unroll
    for (int j = 0; j < CHK; ++j) P3_BODY(i0 + j)
  } else {
    for (int i = i0; i < end; ++i) P3_BODY(i)
  }
#undef P3_BODY
}

// ---------------- host launch ----------------
extern "C" void kernel_launch(void* const* d_in, const int* in_sizes, int n_in,
                              void* d_out, int out_size, void* d_ws, size_t ws_size,
                              hipStream_t stream) {
  const float* x      = (const float*)d_in[0];
  const float* x0     = (const float*)d_in[1];
  const float* W_in   = (const float*)d_in[2];
  const float* W_seli = (const float*)d_in[3];
  const float* W_selo = (const float*)d_in[4];
  const float* W_out  = (const float*)d_in[5];
  const float* d_par  = (const float*)d_in[6];
  const float* ssm_s  = (const float*)d_in[7];
  const float* mlp_s  = (const float*)d_in[8];
  const float* rmix   = (const float*)d_in[9];
  const float* W_fc   = (const float*)d_in[10];
  const float* W_proj = (const float*)d_in[11];
  const int*   tok    = (const int*)d_in[12];
  float* out = (float*)d_out;

  char* p = (char*)d_ws;
  u16* wt_cat  = (u16*)p; p += (size_t)NE * NCAT * DIM * 2;
  u16* wt_selo = (u16*)p; p += (size_t)NE * 4 * KS * HSEL * 2;
  u16* wt_out  = (u16*)p; p += (size_t)NE * DIM * KS * 2;
  u16* wt_fc   = (u16*)p; p += (size_t)DFF * DIM * 2;
  u16* wt_pr   = (u16*)p; p += (size_t)DIM * DFF * 2;
  u16* xs      = (u16*)p; p += (size_t)T_TOK * DIM * 2;
  u16* sh      = (u16*)p; p += (size_t)T_TOK * HSEL * 2;
  u16* sel     = (u16*)p; p += (size_t)T_TOK * 4 * KS * 2;
  u16* yst     = (u16*)p; p += (size_t)T_TOK * KS * 2;
  u16* xn2     = (u16*)p; p += (size_t)T_TOK * DIM * 2;
  u16* hmid    = (u16*)p; p += (size_t)T_TOK * DFF * 2;
  u16* ubuf    = (u16*)p; p += (size_t)T_TOK * KS * 2;
  float* xmix = (float*)p; p += (size_t)T_TOK * DIM * 4;
  float* x2   = (float*)p; p += (size_t)T_TOK * DIM * 4;
  float* Pbuf = (float*)p; p += (size_t)8 * MAXCH * KS * 4;
  float* Sbuf = (float*)p; p += (size_t)8 * MAXCH * KS * 4;
  float* Cbuf = (float*)p; p += (size_t)8 * MAXCH * KS * 4;
  int* perm = (int*)p; p += (size_t)T_TOK * 4;
  int* tpos = (int*)p; p += (size_t)T_TOK * 4;
  int* goff = (int*)p; p += 16 * 4;

  TJobs tj;
  tj.in[0] = W_in;   tj.out[0] = wt_cat;
  tj.in[1] = W_seli; tj.out[1] = wt_cat;
  tj.in[2] = W_selo; tj.out[2] = wt_selo;
  tj.in[3] = W_out;  tj.out[3] = wt_out;
  tj.in[4] = W_fc;   tj.out[4] = wt_fc;
  tj.in[5] = W_proj; tj.out[5] = wt_pr;
  transpose_all<<<18944, dim3(32, 8, 1), 0, stream>>>(tj);

  routing_kernel<<<1, 256, 0, stream>>>(tok, perm, tpos, goff);
  ew_rms<true><<<T_TOK, 256, 0, stream>>>(x, x0, rmix, xmix, tpos, xs);

  // fused u + silu(sel_in): grouped, N=1152
  gemm_t<64, 64, 1, 6><<<dim3(64, NCAT / 64, NE), 256, 0, stream>>>(
      xs, wt_cat, DIM, NCAT, 0, perm, goff, nullptr, ubuf, sh, nullptr, nullptr);
  // sel_out: grouped, N=4096, K=128
  gemm_t<64, 128, 1, 2><<<dim3(64, 32, NE), 256, 0, stream>>>(
      sh, wt_selo, HSEL, 4 * KS, 0, perm, goff, nullptr, sel, nullptr, nullptr, nullptr);
  // recurrence: CHK=8 -> ~512 active blocks for p1/p3
  scan_p1<<<dim3(MAXCH, 8), 256, 0, stream>>>(ubuf, sel, goff, Pbuf, Sbuf);
  scan_p2<<<dim3(8, 4), 64, 0, stream>>>(Pbuf, Sbuf, goff, Cbuf);
  scan_p3<<<dim3(MAXCH, 8), 256, 0, stream>>>(ubuf, sel, goff, Cbuf, d_par, yst);
  // routed out-proj + residual scatter
  gemm_t<64, 64, 1, 3><<<dim3(64, 16, NE), 256, 0, stream>>>(
      yst, wt_out, KS, DIM, 0, perm, goff, x2, nullptr, nullptr, xmix, ssm_s);
  // MLP
  ew_rms<false><<<T_TOK, 256, 0, stream>>>(x2, nullptr, nullptr, nullptr, nullptr, xn2);
  gemm_t<64, 128, 2, 4><<<dim3(64, 32, 1), 256, 0, stream>>>(
      xn2, wt_fc, DIM, DFF, T_TOK, nullptr, nullptr, nullptr, hmid, nullptr, nullptr, nullptr);
  gemm_t<64, 64, 2, 5><<<dim3(64, 16, 1), 256, 0, stream>>>(
      hmid, wt_pr, DFF, DIM, T_TOK, nullptr, nullptr, out, nullptr, nullptr, x2, mlp_s);
}